// Round 1
// baseline (15693.675 us; speedup 1.0000x reference)
//
#include <hip/hip_runtime.h>
#include <math.h>

#define TT 833          // output timesteps
#define GDIM 1024       // 4*H gates
// LDS carve for recur_k (floats): weights 32768 + hbuf 512 + psum 256 + cst 2048
#define RECUR_SMEM_FLOATS 35584

__device__ __forceinline__ float sigm(float x){ return 1.f/(1.f+expf(-x)); }

// ---------------- level smoothing scan ----------------
__global__ void levels_k(const float* __restrict__ train, const float* __restrict__ ism,
                         float* __restrict__ levs){
  int b = threadIdx.x;
  if (b >= 32) return;
  float a = 1.f/(1.f+expf(-ism[0]));
  const float* tr = train + b*1024;
  float* lv = levs + b*1024;
  float lev = fmaxf(tr[0], 0.1f);
  lv[0] = lev;
  for (int t = 1; t < 1024; ++t){
    lev = fmaxf(a*tr[t] + (1.f-a)*lev, 0.1f);
    lv[t] = lev;
  }
}

// ---------------- normalized input windows x0[t*32+b][168] ----------------
__global__ void win_x_k(const float* __restrict__ train, const float* __restrict__ levs,
                        float* __restrict__ x0){
  int idx = blockIdx.x*256 + threadIdx.x;   // exactly 833*32*168
  int i = idx % 168;
  int r = idx / 168;       // t*32+b
  int b = r & 31;
  int t = r >> 5;
  x0[idx] = train[b*1024 + t + i] / levs[b*1024 + t + 167];
}

// ---------------- out_win -> d_out second half ----------------
__global__ void win_out_k(const float* __restrict__ train, const float* __restrict__ levs,
                          float* __restrict__ ow){
  int idx = blockIdx.x*256 + threadIdx.x;   // exactly 833*32*24
  int o = idx % 24;
  int r = idx / 24;
  int b = r & 31;
  int t = r >> 5;
  ow[idx] = train[b*1024 + 168 + t + o] / levs[b*1024 + t + 167];
}

// ---------------- whh[1024][256] -> whhT[256][1024] ----------------
__global__ void transp_k(const float* __restrict__ w, float* __restrict__ wt){
  int idx = blockIdx.x*256 + threadIdx.x;
  if (idx >= 1024*256) return;
  int k = idx >> 10, g = idx & 1023;
  wt[idx] = w[g*256 + k];
}

// ---------------- generic fp32 GEMM: C[m][n] = A[map(m)][:K] . W[n][:K] + b1 (+b2), opt tanh
// dil==0: map(m)=m (m<Mout). dil>0: m=(j,q) with q=p*32+b over rows=32*dil; t=j*dil+p;
// map = t*32+b if t<833 else zero-row (handles tail padding of the dilated reshape).
__global__ __launch_bounds__(256) void proj_gemm(
    const float* __restrict__ A, const float* __restrict__ W,
    const float* __restrict__ b1, const float* __restrict__ b2,
    float* __restrict__ C, int Mout, int K, int N, int dil, int act)
{
  __shared__ float As[16][68];
  __shared__ float Bs[16][68];
  int tid = threadIdx.x;
  int tx = tid & 15, ty = tid >> 4;
  int m0 = blockIdx.y << 6, n0 = blockIdx.x << 6;
  int amap[4];
  #pragma unroll
  for (int i = 0; i < 4; ++i){
    int m = m0 + (tid >> 4) + i*16;
    int row;
    if (dil == 0){ row = (m < Mout) ? m : -1; }
    else {
      int rows = dil << 5;
      int j = m / rows;
      int q = m - j*rows;
      int t = j*dil + (q >> 5);
      row = (t < TT) ? ((t << 5) + (q & 31)) : -1;
    }
    amap[i] = row;
  }
  float acc[4][4] = {{0.f,0.f,0.f,0.f},{0.f,0.f,0.f,0.f},{0.f,0.f,0.f,0.f},{0.f,0.f,0.f,0.f}};
  int nkt = (K + 15) >> 4;
  for (int kt = 0; kt < nkt; ++kt){
    int kk = (kt << 4) + (tid & 15);
    bool kin = kk < K;
    #pragma unroll
    for (int i = 0; i < 4; ++i){
      int ml = (tid >> 4) + i*16;
      As[tid & 15][ml] = (kin && amap[i] >= 0) ? A[(size_t)amap[i]*K + kk] : 0.f;
      Bs[tid & 15][ml] = kin ? W[(size_t)(n0 + ml)*K + kk] : 0.f;
    }
    __syncthreads();
    #pragma unroll
    for (int k = 0; k < 16; ++k){
      float4 av = *reinterpret_cast<const float4*>(&As[k][ty << 2]);
      float4 bv = *reinterpret_cast<const float4*>(&Bs[k][tx << 2]);
      float a4[4] = {av.x, av.y, av.z, av.w};
      float b4[4] = {bv.x, bv.y, bv.z, bv.w};
      #pragma unroll
      for (int i = 0; i < 4; ++i)
        #pragma unroll
        for (int j = 0; j < 4; ++j)
          acc[i][j] = fmaf(a4[i], b4[j], acc[i][j]);
    }
    __syncthreads();
  }
  #pragma unroll
  for (int i = 0; i < 4; ++i){
    int m = m0 + (ty << 2) + i;
    if (m >= Mout) continue;
    #pragma unroll
    for (int j = 0; j < 4; ++j){
      int n = n0 + (tx << 2) + j;
      float v = acc[i][j] + b1[n] + (b2 ? b2[n] : 0.f);
      if (act) v = tanhf(v);
      C[(size_t)m*N + n] = v;
    }
  }
}

// ---------------- persistent dilated-LSTM recurrence ----------------
// grid = 256 = 32 chunks x 8 slices; slice owns h[slice*32 .. +32) i.e. 128 gate rows.
// whh slice preloaded to LDS once. h exchanged via global hstate (double buffered),
// per-chunk arrival counter (device-scope release/acquire) syncs the 8 slices.
// blockIdx = slice*32 + chunk so all slices of a chunk share blk%8 (same-XCD heuristic).
__global__ __launch_bounds__(256,1) void recur_k(
    const float* __restrict__ Gin, const float* __restrict__ whhT,
    float* __restrict__ hstate, float* __restrict__ out, const float* __restrict__ res,
    int* __restrict__ cntbase, int nsteps, int R /* == dilation; rows = 32*R */)
{
  extern __shared__ float sm[];
  float2* wl = reinterpret_cast<float2*>(sm);   // [k2][128] float2 (k-major pairs)
  float* hbuf = sm + 32768;                     // 512 (2 rows x 256)
  float* psum = sm + 33280;                     // 256
  float* cst  = sm + 33536;                     // R*32 cell states
  const int tid = threadIdx.x;
  const int chunk = blockIdx.x & 31;
  const int slice = blockIdx.x >> 5;
  const int rows = R << 5;
  const int hsz = rows << 8;
  int* cnt = cntbase + chunk*16;

  for (int e = tid; e < 16384; e += 256){
    int gg = e & 127, k2 = e >> 7;
    int gr = ((gg >> 5) << 8) + (slice << 5) + (gg & 31);   // i/f/g/o gate row
    wl[e] = make_float2(whhT[(size_t)(k2*2)*GDIM + gr], whhT[(size_t)(k2*2+1)*GDIM + gr]);
  }
  for (int e = tid; e < (R << 5); e += 256) cst[e] = 0.f;
  for (int e = tid; e < (R << 5); e += 256){
    int r = e >> 5, j = e & 31;
    hstate[((chunk*R + r) << 8) + (slice << 5) + j] = 0.f;
  }
  __syncthreads();
  if (tid == 0){
    __threadfence();
    __hip_atomic_fetch_add(cnt, 1, __ATOMIC_RELEASE, __HIP_MEMORY_SCOPE_AGENT);
    while (__hip_atomic_load(cnt, __ATOMIC_ACQUIRE, __HIP_MEMORY_SCOPE_AGENT) < 8) {}
  }
  __syncthreads();

  for (int step = 0; step < nsteps; ++step){
    const int rp = step & 1;
    const float* hsr = hstate + (size_t)rp*hsz;
    float* hsw = hstate + (size_t)(1-rp)*hsz;
    if (R == 1){
      hbuf[tid] = hsr[(chunk << 8) + tid];
      __syncthreads();
      {
        int gg = tid & 127, half = tid >> 7;
        int gr = ((gg >> 5) << 8) + (slice << 5) + (gg & 31);
        float acc = half ? 0.f : Gin[(size_t)((step << 5) + chunk)*GDIM + gr];
        const float2* h2 = reinterpret_cast<const float2*>(hbuf) + (half << 6);
        const float2* w2 = wl + ((half << 6) << 7);
        #pragma unroll 8
        for (int k2 = 0; k2 < 64; ++k2){
          float2 wv = w2[(k2 << 7) + gg];
          float2 hv = h2[k2];
          acc = fmaf(wv.x, hv.x, acc);
          acc = fmaf(wv.y, hv.y, acc);
        }
        psum[tid] = acc;
      }
      __syncthreads();
      if (tid < 32){
        float iv = psum[tid]      + psum[tid + 128];
        float fv = psum[tid + 32] + psum[tid + 160];
        float gv = psum[tid + 64] + psum[tid + 192];
        float ov = psum[tid + 96] + psum[tid + 224];
        float c = cst[tid];
        c = sigm(fv)*c + sigm(iv)*tanhf(gv);
        float h = sigm(ov)*tanhf(c);
        cst[tid] = c;
        hsw[(chunk << 8) + (slice << 5) + tid] = h;
        int t = step;               // d=1: p=0, b=chunk
        if (t < TT){
          size_t oi = (size_t)((t << 5) + chunk)*256 + (slice << 5) + tid;
          float v = h;
          if (res) v += res[oi];
          out[oi] = v;
        }
      }
    } else {
      for (int r0 = 0; r0 < R; r0 += 2){
        for (int e = tid; e < 512; e += 256)
          hbuf[e] = hsr[((chunk*R + r0 + (e >> 8)) << 8) + (e & 255)];
        __syncthreads();
        {
          int gg = tid & 127, rr = tid >> 7;
          int q = chunk*R + r0 + rr;
          int gr = ((gg >> 5) << 8) + (slice << 5) + (gg & 31);
          float acc = Gin[(size_t)(step*rows + q)*GDIM + gr];
          const float2* h2 = reinterpret_cast<const float2*>(hbuf) + (rr << 7);
          #pragma unroll 8
          for (int k2 = 0; k2 < 128; ++k2){
            float2 wv = wl[(k2 << 7) + gg];
            float2 hv = h2[k2];
            acc = fmaf(wv.x, hv.x, acc);
            acc = fmaf(wv.y, hv.y, acc);
          }
          psum[tid] = acc;
        }
        __syncthreads();
        if (tid < 64){
          int rr = tid >> 5, j = tid & 31;
          int q = chunk*R + r0 + rr;
          float iv = psum[(rr << 7) + j];
          float fv = psum[(rr << 7) + 32 + j];
          float gv = psum[(rr << 7) + 64 + j];
          float ov = psum[(rr << 7) + 96 + j];
          float c = cst[((r0 + rr) << 5) + j];
          c = sigm(fv)*c + sigm(iv)*tanhf(gv);
          float h = sigm(ov)*tanhf(c);
          cst[((r0 + rr) << 5) + j] = c;
          hsw[(q << 8) + (slice << 5) + j] = h;
          int p = q >> 5, b = q & 31;
          int t = step*R + p;
          if (t < TT){
            size_t oi = (size_t)((t << 5) + b)*256 + (slice << 5) + j;
            float v = h;
            if (res) v += res[oi];
            out[oi] = v;
          }
        }
        __syncthreads();
      }
    }
    __syncthreads();
    if (tid == 0){
      __threadfence();
      __hip_atomic_fetch_add(cnt, 1, __ATOMIC_RELEASE, __HIP_MEMORY_SCOPE_AGENT);
      const int target = (step + 2) << 3;
      while (__hip_atomic_load(cnt, __ATOMIC_ACQUIRE, __HIP_MEMORY_SCOPE_AGENT) < target) {}
    }
    __syncthreads();
  }
}

// ---------------- scoring head: pred[m][24] = xt[m][:] . sc_w[n][:] + sc_b ----------------
__global__ __launch_bounds__(256) void sc_head(const float* __restrict__ xt, const float* __restrict__ w,
                        const float* __restrict__ bias, float* __restrict__ outp, int M){
  __shared__ float arow[8][256];
  int m0 = blockIdx.x << 3;
  int tid = threadIdx.x;
  #pragma unroll
  for (int i = 0; i < 8; ++i){
    int e = tid + (i << 8);
    int r = e >> 8, k = e & 255;
    arow[r][k] = (m0 + r < M) ? xt[(size_t)(m0 + r)*256 + k] : 0.f;
  }
  __syncthreads();
  int r = tid >> 5, n = tid & 31;
  if (n < 24 && (m0 + r) < M){
    float acc = bias[n];
    const float* wr = w + n*256;
    #pragma unroll 8
    for (int k = 0; k < 256; ++k) acc = fmaf(arow[r][k], wr[k], acc);
    outp[(size_t)(m0 + r)*24 + n] = acc;
  }
}

extern "C" void kernel_launch(void* const* d_in, const int* in_sizes, int n_in,
                              void* d_out, int out_size, void* d_ws, size_t ws_size,
                              hipStream_t stream){
  const float* train = (const float*)d_in[0];
  const float* ism   = (const float*)d_in[4];
  const float* wih[4] = {(const float*)d_in[5], (const float*)d_in[9], (const float*)d_in[13], (const float*)d_in[17]};
  const float* whh[4] = {(const float*)d_in[6], (const float*)d_in[10], (const float*)d_in[14], (const float*)d_in[18]};
  const float* bih[4] = {(const float*)d_in[7], (const float*)d_in[11], (const float*)d_in[15], (const float*)d_in[19]};
  const float* bhh[4] = {(const float*)d_in[8], (const float*)d_in[12], (const float*)d_in[16], (const float*)d_in[20]};
  const float* nl_w = (const float*)d_in[21];
  const float* nl_b = (const float*)d_in[22];
  const float* sc_w = (const float*)d_in[23];
  const float* sc_b = (const float*)d_in[24];
  float* out = (float*)d_out;

  float* ws = (float*)d_ws;
  size_t off = 0;
  float* levs = ws + off;   off += 32768;
  int*   cnt  = (int*)(ws + off); off += 2048;          // 4 layers * 32 chunks * 16-int stride
  float* whhT = ws + off;   off += (size_t)4*262144;
  float* hstate = ws + off; off += (size_t)2*2048*256;
  float* x0 = ws + off;     off += (size_t)26656*168;
  float* G  = ws + off;     off += (size_t)28672*1024;
  float* h0 = ws + off;     off += (size_t)26656*256;
  float* h1 = ws + off;     off += (size_t)26656*256;
  float* h2 = ws + off;     off += (size_t)26656*256;
  (void)ws_size; (void)in_sizes; (void)n_in; (void)out_size;

  hipMemsetAsync(cnt, 0, 2048*sizeof(int), stream);
  levels_k<<<1, 64, 0, stream>>>(train, ism, levs);
  win_x_k<<<17493, 256, 0, stream>>>(train, levs, x0);
  win_out_k<<<2499, 256, 0, stream>>>(train, levs, out + 639744);
  for (int l = 0; l < 4; ++l)
    transp_k<<<1024, 256, 0, stream>>>(whh[l], whhT + (size_t)l*262144);

  const int SMEM = RECUR_SMEM_FLOATS*4;
  hipFuncSetAttribute(reinterpret_cast<const void*>(recur_k),
                      hipFuncAttributeMaxDynamicSharedMemorySize, SMEM);

  // layer 0 (d=1): 833 steps, rows=32
  proj_gemm<<<dim3(16,417), 256, 0, stream>>>(x0, wih[0], bih[0], bhh[0], G, 26656, 168, 1024, 0, 0);
  recur_k<<<256, 256, SMEM, stream>>>(G, whhT + 0, hstate, h0, nullptr, cnt + 0, 833, 1);
  // layer 1 (d=4): 209 steps, rows=128
  proj_gemm<<<dim3(16,418), 256, 0, stream>>>(h0, wih[1], bih[1], bhh[1], G, 26752, 256, 1024, 4, 0);
  recur_k<<<256, 256, SMEM, stream>>>(G, whhT + 262144, hstate, h1, nullptr, cnt + 32*16, 209, 4);
  // layer 2 (d=16): 53 steps, rows=512
  proj_gemm<<<dim3(16,424), 256, 0, stream>>>(h1, wih[2], bih[2], bhh[2], G, 27136, 256, 1024, 16, 0);
  recur_k<<<256, 256, SMEM, stream>>>(G, whhT + 2*262144, hstate, h2, nullptr, cnt + 64*16, 53, 16);
  // layer 3 (d=64): 14 steps, rows=2048, residual = h1 (group-1 skip), out overwrites h2 (xf)
  proj_gemm<<<dim3(16,448), 256, 0, stream>>>(h2, wih[3], bih[3], bhh[3], G, 28672, 256, 1024, 64, 0);
  recur_k<<<256, 256, SMEM, stream>>>(G, whhT + 3*262144, hstate, h2, h1, cnt + 96*16, 14, 64);
  // nonlinear dense: xt = tanh(xf @ nl_w.T + nl_b)  (reuse h0)
  proj_gemm<<<dim3(4,417), 256, 0, stream>>>(h2, nl_w, nl_b, nullptr, h0, 26656, 256, 256, 0, 1);
  // scoring head -> pred (first half of d_out)
  sc_head<<<3332, 256, 0, stream>>>(h0, sc_w, sc_b, out, 26656);
}